// Round 5
// baseline (105.845 us; speedup 1.0000x reference)
//
#include <hip/hip_runtime.h>

#define B_ 32
#define T_ 8192
#define F_ 256
#define H_ 128

typedef short bf16x8 __attribute__((ext_vector_type(8)));
typedef float f32x4  __attribute__((ext_vector_type(4)));

// Hardware packed f32->bf16 RNE conversion (1 VALU op for 2 values).
static __device__ __forceinline__ unsigned int pack_bf2(float lo, float hi) {
    unsigned int r;
    asm("v_cvt_pk_bf16_f32 %0, %1, %2" : "=v"(r) : "v"(lo), "v"(hi));
    return r;
}

// tanh(x) = 1 - 2/(e^{2x}+1) via v_exp_f32 (exp2). No clamp needed:
// e^{+inf}=inf -> rcp=0 -> 1; e^{-inf}=0 -> 1-2 = -1. |err| ~1e-6.
static __device__ __forceinline__ float fast_tanh(float x) {
    float e = __builtin_amdgcn_exp2f(x * 2.8853900817779268f);  // e^{2x}
    return 1.f - 2.f * __builtin_amdgcn_rcpf(e + 1.f);
}

// ws layout: [0, 16KB): w2d = dec@W2, fp32 [32][128]
//            [16KB, 80KB): W1 bf16 fragments, 4096 entries * 16B
// Fragment entry e = (nt*8 + ks)*64 + lane ; entry[j] = bf16(W1[f][h])
//   with q = lane>>4, c = lane&15, h = 16*nt + c, f = 64*q + 8*ks + j
__global__ __launch_bounds__(256) void prep_kernel(const float* __restrict__ dec,
                                                   const float* __restrict__ W1,
                                                   const float* __restrict__ W2,
                                                   float* __restrict__ w2d,
                                                   uint4* __restrict__ frags) {
    const int blk = blockIdx.x, tid = threadIdx.x;
    if (blk < 32) {
        if (tid < H_) {
            const float* dp = dec + blk * F_;
            float s = 0.f;
            #pragma unroll 8
            for (int f = 0; f < F_; ++f) s += dp[f] * W2[f * H_ + tid];
            w2d[blk * H_ + tid] = s;
        }
    } else {
        const int e = (blk - 32) * 256 + tid;   // 0..4095
        const int lane = e & 63;
        const int ks   = (e >> 6) & 7;
        const int nt   = e >> 9;
        const int q = lane >> 4, c = lane & 15;
        const int h = nt * 16 + c;
        const float* src = W1 + (q * 64 + ks * 8) * H_ + h;
        unsigned int u[4];
        #pragma unroll
        for (int jj = 0; jj < 4; ++jj) {
            float a = src[(2 * jj) * H_];
            float b = src[(2 * jj + 1) * H_];
            u[jj] = pack_bf2(a, b);
        }
        frags[e] = uint4{u[0], u[1], u[2], u[3]};
    }
}

// Main: 1024 blocks x 256 threads. Block -> (b = blk>>5, t0 = (blk&31)*256).
// 8 half-tiles of 32 rows, double-buffered LDS, 1 barrier per half-tile.
// Wave w owns h-columns [32w, 32w+32) with W1 frags in registers.
// __launch_bounds__(256,4): 4 waves/EU -> 4 blocks/CU (grid 1024 = exact fit,
// no straggler tail), VGPR capped at 128.
__global__ __launch_bounds__(256, 4) void attn_main(const float* __restrict__ enc,
                                                    const float* __restrict__ Vvec,
                                                    const float* __restrict__ w2d,
                                                    const uint4* __restrict__ frags,
                                                    float* __restrict__ out) {
    __shared__ __align__(16) unsigned char tile_lds[2][32 * 512]; // 2 x 16 KB
    __shared__ float red[4][256];                                 // per-wave row partials

    const int tid  = threadIdx.x;
    const int blk  = blockIdx.x;
    const int b    = blk >> 5;
    const int t0   = (blk & 31) << 8;
    const int w    = tid >> 6;
    const int lane = tid & 63;
    const int q    = lane >> 4;     // A: k-quarter; D: row-group
    const int c    = lane & 15;     // A: row-in-tile16; D: col-in-ntile

    // W1 B-fragments for this wave's 32 columns: 64 VGPRs, loaded once (coalesced)
    bf16x8 bw[2][8];
    #pragma unroll
    for (int ntl = 0; ntl < 2; ++ntl)
        #pragma unroll
        for (int ks = 0; ks < 8; ++ks) {
            uint4 u = frags[((2 * w + ntl) * 8 + ks) * 64 + lane];
            bw[ntl][ks] = __builtin_bit_cast(bf16x8, u);
        }

    float Vv[2], wd[2];
    #pragma unroll
    for (int ntl = 0; ntl < 2; ++ntl) {
        const int h = 16 * (2 * w + ntl) + c;
        Vv[ntl] = Vvec[h];
        wd[ntl] = w2d[b * H_ + h];
    }

    const f32x4* src = (const f32x4*)(enc + ((size_t)b * T_ + t0) * F_);
    const int sw = c & 7;

    // Prologue: issue loads for half-tile 0 (8 coalesced dwordx4 per thread)
    f32x4 x[8];
    #pragma unroll
    for (int i = 0; i < 8; ++i) x[i] = src[i * 256 + tid];

    for (int ht = 0; ht < 8; ++ht) {
        const int cur = ht & 1;
        unsigned char* buf = tile_lds[cur];

        // ---- pack regs -> bf16 (hw cvt_pk) -> swizzled LDS (frees x) ----
        #pragma unroll
        for (int i = 0; i < 8; ++i) {
            const int flat4 = i * 256 + tid;   // 0..2047
            const int row   = flat4 >> 6;      // 0..31
            const int c4    = flat4 & 63;      // f32x4 chunk in row
            const int chunk = (c4 >> 1) ^ (row & 7);
            uint2 v;
            v.x = pack_bf2(x[i][0], x[i][1]);
            v.y = pack_bf2(x[i][2], x[i][3]);
            *(uint2*)(buf + row * 512 + chunk * 16 + (c4 & 1) * 8) = v;
        }

        // ---- issue next half-tile's global loads (land during compute) ----
        if (ht < 7) {
            const f32x4* sp = src + (ht + 1) * 2048;
            #pragma unroll
            for (int i = 0; i < 8; ++i) x[i] = sp[i * 256 + tid];
        }

        __syncthreads();   // writes to buf visible; single barrier per iter

        // ---- compute 2 row-groups of 16; K=256 via 8 MFMA steps x 2 ntiles ----
        #pragma unroll
        for (int g = 0; g < 2; ++g) {
            const unsigned char* rbase = buf + (g * 16 + c) * 512;
            f32x4 acc0 = {0.f, 0.f, 0.f, 0.f};
            f32x4 acc1 = {0.f, 0.f, 0.f, 0.f};
            #pragma unroll
            for (int ks = 0; ks < 8; ++ks) {
                bf16x8 a = *(const bf16x8*)(rbase + ((8 * q + ks) ^ sw) * 16);
                acc0 = __builtin_amdgcn_mfma_f32_16x16x32_bf16(a, bw[0][ks], acc0, 0, 0, 0);
                acc1 = __builtin_amdgcn_mfma_f32_16x16x32_bf16(a, bw[1][ks], acc1, 0, 0, 0);
            }
            f32x4 part;
            #pragma unroll
            for (int r = 0; r < 4; ++r)
                part[r] = Vv[0] * fast_tanh(acc0[r] + wd[0])
                        + Vv[1] * fast_tanh(acc1[r] + wd[1]);
            #pragma unroll
            for (int m = 1; m < 16; m <<= 1) {
                #pragma unroll
                for (int r = 0; r < 4; ++r) part[r] += __shfl_xor(part[r], m, 64);
            }
            if (c == 0)
                *(f32x4*)&red[w][ht * 32 + g * 16 + 4 * q] = part;
        }
        // no second barrier: next iter writes the OTHER LDS buffer
    }

    __syncthreads();
    // ---- combine 4 wave-partials for all 256 rows, coalesced store ----
    {
        float s = red[0][tid] + red[1][tid] + red[2][tid] + red[3][tid];
        out[(size_t)b * T_ + t0 + tid] = s;
    }
}

extern "C" void kernel_launch(void* const* d_in, const int* in_sizes, int n_in,
                              void* d_out, int out_size, void* d_ws, size_t ws_size,
                              hipStream_t stream) {
    const float* enc = (const float*)d_in[0];
    const float* dec = (const float*)d_in[1];
    const float* W1  = (const float*)d_in[2];
    const float* W2  = (const float*)d_in[3];
    const float* V   = (const float*)d_in[4];
    float* out = (float*)d_out;

    float* w2d   = (float*)d_ws;
    uint4* frags = (uint4*)((char*)d_ws + 16384);

    prep_kernel<<<48, 256, 0, stream>>>(dec, W1, W2, w2d, frags);
    attn_main<<<1024, 256, 0, stream>>>(enc, V, w2d, frags, out);
}

// Round 6
// 59.795 us; speedup vs baseline: 1.7701x; 1.7701x over previous
//
#include <hip/hip_runtime.h>

#define B_ 32
#define T_ 8192
#define F_ 256
#define H_ 128

typedef short bf16x8 __attribute__((ext_vector_type(8)));
typedef float f32x4  __attribute__((ext_vector_type(4)));

// Hardware packed f32->bf16 RNE conversion (1 VALU op for 2 values).
static __device__ __forceinline__ unsigned int pack_bf2(float lo, float hi) {
    unsigned int r;
    asm("v_cvt_pk_bf16_f32 %0, %1, %2" : "=v"(r) : "v"(lo), "v"(hi));
    return r;
}

// tanh(x) = 1 - 2/(e^{2x}+1) via v_exp_f32 (exp2). No clamp needed:
// e^{+inf}=inf -> rcp=0 -> 1; e^{-inf}=0 -> 1-2 = -1. |err| ~1e-6.
static __device__ __forceinline__ float fast_tanh(float x) {
    float e = __builtin_amdgcn_exp2f(x * 2.8853900817779268f);  // e^{2x}
    return 1.f - 2.f * __builtin_amdgcn_rcpf(e + 1.f);
}

// ws layout: [0, 16KB): w2d = dec@W2, fp32 [32][128]
//            [16KB, 80KB): W1 bf16 fragments, 4096 entries * 16B
// Fragment entry e = (nt*8 + ks)*64 + lane ; entry[j] = bf16(W1[f][h])
//   with q = lane>>4, c = lane&15, h = 16*nt + c, f = 64*q + 8*ks + j
__global__ __launch_bounds__(256) void prep_kernel(const float* __restrict__ dec,
                                                   const float* __restrict__ W1,
                                                   const float* __restrict__ W2,
                                                   float* __restrict__ w2d,
                                                   uint4* __restrict__ frags) {
    const int blk = blockIdx.x, tid = threadIdx.x;
    if (blk < 32) {
        if (tid < H_) {
            const float* dp = dec + blk * F_;
            float s = 0.f;
            #pragma unroll 8
            for (int f = 0; f < F_; ++f) s += dp[f] * W2[f * H_ + tid];
            w2d[blk * H_ + tid] = s;
        }
    } else {
        const int e = (blk - 32) * 256 + tid;   // 0..4095
        const int lane = e & 63;
        const int ks   = (e >> 6) & 7;
        const int nt   = e >> 9;
        const int q = lane >> 4, c = lane & 15;
        const int h = nt * 16 + c;
        const float* src = W1 + (q * 64 + ks * 8) * H_ + h;
        unsigned int u[4];
        #pragma unroll
        for (int jj = 0; jj < 4; ++jj) {
            float a = src[(2 * jj) * H_];
            float b = src[(2 * jj + 1) * H_];
            u[jj] = pack_bf2(a, b);
        }
        frags[e] = uint4{u[0], u[1], u[2], u[3]};
    }
}

// Main: 1024 blocks x 256 threads. Block -> (b = blk>>5, t0 = (blk&31)*256).
// 8 half-tiles of 32 rows, double-buffered LDS, 1 barrier per half-tile.
// Wave w owns h-columns [32w, 32w+32) with W1 frags in registers.
// NOTE: no min-waves bound — forcing 4 waves/EU (VGPR<=128) spills and
// regressed 60.6 -> 105.8 us in round 5. Natural allocation ~150 VGPR.
__global__ __launch_bounds__(256) void attn_main(const float* __restrict__ enc,
                                                 const float* __restrict__ Vvec,
                                                 const float* __restrict__ w2d,
                                                 const uint4* __restrict__ frags,
                                                 float* __restrict__ out) {
    __shared__ __align__(16) unsigned char tile_lds[2][32 * 512]; // 2 x 16 KB
    __shared__ float red[4][256];                                 // per-wave row partials

    const int tid  = threadIdx.x;
    const int blk  = blockIdx.x;
    const int b    = blk >> 5;
    const int t0   = (blk & 31) << 8;
    const int w    = tid >> 6;
    const int lane = tid & 63;
    const int q    = lane >> 4;     // A: k-quarter; D: row-group
    const int c    = lane & 15;     // A: row-in-tile16; D: col-in-ntile

    // W1 B-fragments for this wave's 32 columns: 64 VGPRs, loaded once (coalesced)
    bf16x8 bw[2][8];
    #pragma unroll
    for (int ntl = 0; ntl < 2; ++ntl)
        #pragma unroll
        for (int ks = 0; ks < 8; ++ks) {
            uint4 u = frags[((2 * w + ntl) * 8 + ks) * 64 + lane];
            bw[ntl][ks] = __builtin_bit_cast(bf16x8, u);
        }

    float Vv[2], wd[2];
    #pragma unroll
    for (int ntl = 0; ntl < 2; ++ntl) {
        const int h = 16 * (2 * w + ntl) + c;
        Vv[ntl] = Vvec[h];
        wd[ntl] = w2d[b * H_ + h];
    }

    const f32x4* src = (const f32x4*)(enc + ((size_t)b * T_ + t0) * F_);
    const int sw = c & 7;

    // Prologue: issue loads for half-tile 0 (8 coalesced dwordx4 per thread)
    f32x4 x[8];
    #pragma unroll
    for (int i = 0; i < 8; ++i) x[i] = src[i * 256 + tid];

    for (int ht = 0; ht < 8; ++ht) {
        const int cur = ht & 1;
        unsigned char* buf = tile_lds[cur];

        // ---- pack regs -> bf16 (hw cvt_pk) -> swizzled LDS (frees x) ----
        #pragma unroll
        for (int i = 0; i < 8; ++i) {
            const int flat4 = i * 256 + tid;   // 0..2047
            const int row   = flat4 >> 6;      // 0..31
            const int c4    = flat4 & 63;      // f32x4 chunk in row
            const int chunk = (c4 >> 1) ^ (row & 7);
            uint2 v;
            v.x = pack_bf2(x[i][0], x[i][1]);
            v.y = pack_bf2(x[i][2], x[i][3]);
            *(uint2*)(buf + row * 512 + chunk * 16 + (c4 & 1) * 8) = v;
        }

        // ---- issue next half-tile's global loads (land during compute) ----
        if (ht < 7) {
            const f32x4* sp = src + (ht + 1) * 2048;
            #pragma unroll
            for (int i = 0; i < 8; ++i) x[i] = sp[i * 256 + tid];
        }

        __syncthreads();   // writes to buf visible; single barrier per iter

        // ---- compute 2 row-groups of 16; K=256 via 8 MFMA steps x 2 ntiles ----
        #pragma unroll
        for (int g = 0; g < 2; ++g) {
            const unsigned char* rbase = buf + (g * 16 + c) * 512;
            f32x4 acc0 = {0.f, 0.f, 0.f, 0.f};
            f32x4 acc1 = {0.f, 0.f, 0.f, 0.f};
            #pragma unroll
            for (int ks = 0; ks < 8; ++ks) {
                bf16x8 a = *(const bf16x8*)(rbase + ((8 * q + ks) ^ sw) * 16);
                acc0 = __builtin_amdgcn_mfma_f32_16x16x32_bf16(a, bw[0][ks], acc0, 0, 0, 0);
                acc1 = __builtin_amdgcn_mfma_f32_16x16x32_bf16(a, bw[1][ks], acc1, 0, 0, 0);
            }
            f32x4 part;
            #pragma unroll
            for (int r = 0; r < 4; ++r)
                part[r] = Vv[0] * fast_tanh(acc0[r] + wd[0])
                        + Vv[1] * fast_tanh(acc1[r] + wd[1]);
            #pragma unroll
            for (int m = 1; m < 16; m <<= 1) {
                #pragma unroll
                for (int r = 0; r < 4; ++r) part[r] += __shfl_xor(part[r], m, 64);
            }
            if (c == 0)
                *(f32x4*)&red[w][ht * 32 + g * 16 + 4 * q] = part;
        }
        // no second barrier: next iter writes the OTHER LDS buffer
    }

    __syncthreads();
    // ---- combine 4 wave-partials for all 256 rows, coalesced store ----
    {
        float s = red[0][tid] + red[1][tid] + red[2][tid] + red[3][tid];
        out[(size_t)b * T_ + t0 + tid] = s;
    }
}

extern "C" void kernel_launch(void* const* d_in, const int* in_sizes, int n_in,
                              void* d_out, int out_size, void* d_ws, size_t ws_size,
                              hipStream_t stream) {
    const float* enc = (const float*)d_in[0];
    const float* dec = (const float*)d_in[1];
    const float* W1  = (const float*)d_in[2];
    const float* W2  = (const float*)d_in[3];
    const float* V   = (const float*)d_in[4];
    float* out = (float*)d_out;

    float* w2d   = (float*)d_ws;
    uint4* frags = (uint4*)((char*)d_ws + 16384);

    prep_kernel<<<48, 256, 0, stream>>>(dec, W1, W2, w2d, frags);
    attn_main<<<1024, 256, 0, stream>>>(enc, V, w2d, frags, out);
}

// Round 7
// 53.849 us; speedup vs baseline: 1.9656x; 1.1104x over previous
//
#include <hip/hip_runtime.h>

#define B_ 32
#define T_ 8192
#define F_ 256
#define H_ 128

typedef short bf16x8 __attribute__((ext_vector_type(8)));
typedef float f32x4  __attribute__((ext_vector_type(4)));

// Hardware packed f32->bf16 RNE conversion (1 VALU op for 2 values).
static __device__ __forceinline__ unsigned int pack_bf2(float lo, float hi) {
    unsigned int r;
    asm("v_cvt_pk_bf16_f32 %0, %1, %2" : "=v"(r) : "v"(lo), "v"(hi));
    return r;
}

// tanh(x) = 1 - 2/(e^{2x}+1) via v_exp_f32 (exp2). No clamp needed:
// e^{+inf}=inf -> rcp=0 -> 1; e^{-inf}=0 -> 1-2 = -1. |err| ~1e-6.
static __device__ __forceinline__ float fast_tanh(float x) {
    float e = __builtin_amdgcn_exp2f(x * 2.8853900817779268f);  // e^{2x}
    return 1.f - 2.f * __builtin_amdgcn_rcpf(e + 1.f);
}

// Single fused kernel: 512 blocks x 512 threads (8 waves).
// Block -> (b = blk>>4, t0 = (blk&15)*512); 16 half-tiles of 32 rows.
// Wave w owns ntile w (h-columns [16w,16w+16)), W1 frags in registers (32 VGPR).
// Staging: reg-staged f32->bf16 (cvt_pk) -> XOR-swizzled LDS, double-buffered.
// KEY: barrier is raw s_barrier + lgkmcnt(0) ONLY (no vmcnt drain), so the
// next half-tile's global loads stay in flight across the barrier and the
// whole compute phase — __syncthreads would drain vmcnt(0) and serialize.
// Race analysis (1 barrier/iter): wave A writes buf[i&1] at iter i+2 only
// after barrier i+1, which every wave reaches only after finishing compute
// of iter i (its reads of buf[i&1]). Safe.
// NOTE: no min-waves bound — forcing VGPR<=128 via launch_bounds spilled and
// regressed 60.6->105.8 us (round 5). This structure fits ~100 VGPR naturally.
__global__ __launch_bounds__(512) void attn_fused(const float* __restrict__ enc,
                                                  const float* __restrict__ dec,
                                                  const float* __restrict__ W1,
                                                  const float* __restrict__ W2,
                                                  const float* __restrict__ Vvec,
                                                  float* __restrict__ out) {
    __shared__ __align__(16) unsigned char tile_lds[2][32 * 512]; // 2 x 16 KB
    __shared__ float red[8][512];    // 16 KB: per-wave row partials
    __shared__ float w2dp[4][128];   // w2d partial sums
    __shared__ float w2dv[128];      // w2d[b][:]

    const int tid  = threadIdx.x;
    const int blk  = blockIdx.x;
    const int b    = blk >> 4;
    const int t0   = (blk & 15) << 9;
    const int w    = tid >> 6;
    const int lane = tid & 63;
    const int q    = lane >> 4;     // A: k-quarter; D: row-group
    const int c    = lane & 15;     // A: row-in-tile16; D: col-in-ntile

    const f32x4* src = (const f32x4*)(enc + ((size_t)b * T_ + t0) * F_);

    // ---- issue half-tile 0 loads first: HBM/L3 latency overlaps init ----
    f32x4 x[4];
    #pragma unroll
    for (int i = 0; i < 4; ++i) x[i] = src[i * 512 + tid];

    // ---- W1 -> B-fragments in registers (wave w owns ntile w) ----
    // bw[ks][j] = bf16(W1[64q + 8ks + j][h]), h = 16w + c. L2-served.
    const int h = 16 * w + c;
    bf16x8 bw[8];
    #pragma unroll
    for (int ks = 0; ks < 8; ++ks) {
        const float* wp = W1 + (64 * q + 8 * ks) * H_ + h;
        union { bf16x8 v; unsigned int u[4]; } pk;
        #pragma unroll
        for (int jj = 0; jj < 4; ++jj)
            pk.u[jj] = pack_bf2(wp[(2 * jj) * H_], wp[(2 * jj + 1) * H_]);
        bw[ks] = pk.v;
    }

    // ---- w2d[b][hh] = dec[b]@W2[:,hh], 4-way f-split (fp32 exact) ----
    {
        const int hh = tid & 127, p = tid >> 7;
        const float* dp  = dec + b * F_ + p * 64;      // uniform -> scalar loads
        const float* w2p = W2 + (p * 64) * H_ + hh;    // coalesced per f
        float s = 0.f;
        #pragma unroll 8
        for (int f = 0; f < 64; ++f) s += dp[f] * w2p[f * H_];
        w2dp[p][hh] = s;
    }
    __syncthreads();
    if (tid < 128)
        w2dv[tid] = w2dp[0][tid] + w2dp[1][tid] + w2dp[2][tid] + w2dp[3][tid];
    __syncthreads();

    const float Vv = Vvec[h];
    const float wd = w2dv[h];
    const int sw = c & 7;

    #pragma unroll 2
    for (int ht = 0; ht < 16; ++ht) {
        unsigned char* buf = tile_lds[ht & 1];

        // ---- pack regs -> bf16 (hw cvt_pk) -> swizzled LDS (frees x) ----
        #pragma unroll
        for (int i = 0; i < 4; ++i) {
            const int flat4 = i * 512 + tid;   // 0..2047
            const int row   = flat4 >> 6;      // 0..31
            const int c4    = flat4 & 63;      // f32x4 chunk in row
            const int chunk = (c4 >> 1) ^ (row & 7);
            uint2 v;
            v.x = pack_bf2(x[i][0], x[i][1]);
            v.y = pack_bf2(x[i][2], x[i][3]);
            *(uint2*)(buf + row * 512 + chunk * 16 + (c4 & 1) * 8) = v;
        }

        // ---- issue next half-tile's loads: stay in flight across barrier ----
        if (ht < 15) {
            const f32x4* sp = src + (ht + 1) * 2048;
            #pragma unroll
            for (int i = 0; i < 4; ++i) x[i] = sp[i * 512 + tid];
        }

        // LDS-writes visible to all waves; global loads NOT drained.
        asm volatile("s_waitcnt lgkmcnt(0)\n\ts_barrier" ::: "memory");

        // ---- compute 2 row-groups of 16; K=256 via 8 MFMA steps ----
        #pragma unroll
        for (int g = 0; g < 2; ++g) {
            const unsigned char* rbase = buf + (g * 16 + c) * 512;
            f32x4 acc = {0.f, 0.f, 0.f, 0.f};
            #pragma unroll
            for (int ks = 0; ks < 8; ++ks) {
                bf16x8 a = *(const bf16x8*)(rbase + ((8 * q + ks) ^ sw) * 16);
                acc = __builtin_amdgcn_mfma_f32_16x16x32_bf16(a, bw[ks], acc, 0, 0, 0);
            }
            f32x4 part;
            #pragma unroll
            for (int r = 0; r < 4; ++r)
                part[r] = Vv * fast_tanh(acc[r] + wd);
            #pragma unroll
            for (int m = 1; m < 16; m <<= 1) {
                #pragma unroll
                for (int r = 0; r < 4; ++r) part[r] += __shfl_xor(part[r], m, 64);
            }
            if (c == 0)
                *(f32x4*)&red[w][ht * 32 + g * 16 + 4 * q] = part;
        }
    }

    __syncthreads();
    // ---- combine 8 wave-partials for all 512 rows, coalesced store ----
    float s = 0.f;
    #pragma unroll
    for (int ww = 0; ww < 8; ++ww) s += red[ww][tid];
    out[(size_t)b * T_ + t0 + tid] = s;
}

extern "C" void kernel_launch(void* const* d_in, const int* in_sizes, int n_in,
                              void* d_out, int out_size, void* d_ws, size_t ws_size,
                              hipStream_t stream) {
    const float* enc = (const float*)d_in[0];
    const float* dec = (const float*)d_in[1];
    const float* W1  = (const float*)d_in[2];
    const float* W2  = (const float*)d_in[3];
    const float* V   = (const float*)d_in[4];
    float* out = (float*)d_out;

    attn_fused<<<512, 512, 0, stream>>>(enc, dec, W1, W2, V, out);
}